// Round 2
// baseline (478.390 us; speedup 1.0000x reference)
//
#include <hip/hip_runtime.h>
#include <math.h>

#define EMBED 512
#define NQ 8
#define SEQ 2048
#define NB 8
#define LOG2E 1.4426950408889634f

typedef float vfloat4 __attribute__((ext_vector_type(4)));

// ---------------------------------------------------------------------------
// k1: rotT[b][q][i] = sum_e x[b][i][e] * R[e][q]   (unchanged — at its 32 MiB
// read roofline, ~6 µs). R transposed through LDS (stride 516, conflict-free
// b128); thread (q = tid&7, rslot = tid>>3) does one K=512 dot with vfloat4.
// ---------------------------------------------------------------------------
#define RPAD 516

__global__ __launch_bounds__(256) void qa_rot(
    const float* __restrict__ x, const float* __restrict__ R,
    float* __restrict__ rotT) {
    __shared__ float rt[NQ * RPAD];
#pragma unroll
    for (int m = 0; m < (EMBED * NQ) / 256; ++m) {
        int f = threadIdx.x + m * 256;
        rt[(f & 7) * RPAD + (f >> 3)] = R[f];
    }
    __syncthreads();

    const int q = threadIdx.x & 7;
    const int rslot = threadIdx.x >> 3;           // 0..31
    const int b = blockIdx.x >> 6;                // 64 blocks per batch
    const int i = ((blockIdx.x & 63) << 5) + rslot;

    const vfloat4* __restrict__ xr =
        (const vfloat4*)(x + ((size_t)b * SEQ + i) * EMBED);
    const vfloat4* __restrict__ rr = (const vfloat4*)(rt + q * RPAD);

    vfloat4 acc = {0.f, 0.f, 0.f, 0.f};           // 4 independent chains
#pragma unroll 8
    for (int m = 0; m < EMBED / 4; ++m) {
        acc += xr[m] * rr[m];                     // packed fma
    }
    rotT[(size_t)b * (NQ * SEQ) + (size_t)q * SEQ + i] =
        (acc.x + acc.y) + (acc.z + acc.w);
}

// ---------------------------------------------------------------------------
// k2 v3: scores[b][i][j] = sigmoid(rot_i . rot_j) / rowsum.
//
// R0 (retained-pv, burst nt stores, 2 residency rounds) and R1 (two-pass
// recompute, spread nt stores, 1 round) both landed at the same dur_us, so
// none of {store timing, residency rounds, trans count, per-row LDS volume}
// binds. What they SHARED: 64 KiB LDS panel -> hard 2 blocks/CU (16 waves/CU,
// 4/SIMD), lockstep stage+barrier, nt stores. This version removes all three:
//
//   - NO LDS, NO barriers. rot_j read straight from global: rotT[b] is
//     64 KiB (512 KiB for all batches) — L1/L2-resident. Wave loads are
//     1 KiB coalesced dwordx4, L1-served on reuse.
//   - 256-thread blocks, __launch_bounds__(256,6) -> ~24 waves/CU; blocks
//     free-run and desync, spreading store traffic in time without choreography.
//   - plain (cached) stores instead of nontemporal — the 6.6 TB/s fill uses
//     cached stores; 128 MiB streaming writes can't meaningfully pollute a
//     512 KiB read working set.
//
// Two-pass recompute keeps live VGPRs low (ri[4][8] mostly in SGPRs via
// wave-uniform loads, s[4] vfloat4, 8 in-flight rj): ~70-80 VGPRs.
// Math is bit-identical to R1 (same q-order dots, sigmoid, butterfly).
// ---------------------------------------------------------------------------
#define K2_THREADS 256
#define TI 4
#define ROWS_PER_BLOCK 16   // 4 waves * TI

__device__ __forceinline__ vfloat4 sigmoid4(vfloat4 s) {
    vfloat4 p;
    p.x = __builtin_amdgcn_rcpf(1.f + __builtin_amdgcn_exp2f(-s.x * LOG2E));
    p.y = __builtin_amdgcn_rcpf(1.f + __builtin_amdgcn_exp2f(-s.y * LOG2E));
    p.z = __builtin_amdgcn_rcpf(1.f + __builtin_amdgcn_exp2f(-s.z * LOG2E));
    p.w = __builtin_amdgcn_rcpf(1.f + __builtin_amdgcn_exp2f(-s.w * LOG2E));
    return p;
}

__global__ __launch_bounds__(K2_THREADS, 6) void qa_scores(
    const float* __restrict__ rotT, float* __restrict__ out) {
    const int b = blockIdx.x >> 7;                // 128 blocks per batch
    const int i0blk = (blockIdx.x & 127) * ROWS_PER_BLOCK;
    const float* __restrict__ rt = rotT + (size_t)b * (NQ * SEQ);

    const int wave = threadIdx.x >> 6;            // 0..3
    const int lane = threadIdx.x & 63;
    const int i0 = i0blk + wave * TI;

    // rot_i for this wave's 4 rows — wave-uniform addresses -> scalar loads.
    float ri[TI][NQ];
#pragma unroll
    for (int r = 0; r < TI; ++r)
#pragma unroll
        for (int q = 0; q < NQ; ++q)
            ri[r][q] = rt[q * SEQ + i0 + r];

    // ---- Pass A: rowsums only. Lane owns j = t*256 + 4*lane .. +3. ----
    float rsum[TI] = {0.f, 0.f, 0.f, 0.f};
#pragma unroll 2
    for (int t = 0; t < 8; ++t) {
        vfloat4 s[TI];
#pragma unroll
        for (int r = 0; r < TI; ++r) s[r] = (vfloat4){0.f, 0.f, 0.f, 0.f};
#pragma unroll
        for (int q = 0; q < NQ; ++q) {            // 8 independent loads/t
            vfloat4 rj = *((const vfloat4*)(rt + q * SEQ + t * 256) + lane);
#pragma unroll
            for (int r = 0; r < TI; ++r)
                s[r] += rj * ri[r][q];            // packed fma
        }
#pragma unroll
        for (int r = 0; r < TI; ++r) {
            vfloat4 p = sigmoid4(s[r]);
            rsum[r] += (p.x + p.y) + (p.z + p.w);
        }
    }

    // Butterfly reduce rowsums over 64 lanes; keep inverse.
    float rinv[TI];
#pragma unroll
    for (int r = 0; r < TI; ++r) {
#pragma unroll
        for (int off = 32; off > 0; off >>= 1)
            rsum[r] += __shfl_xor(rsum[r], off);
        rinv[r] = __builtin_amdgcn_rcpf(rsum[r]);
    }

    // ---- Pass B: recompute (bit-identical), normalize, store per tile. ----
    float* __restrict__ orow0 = out + ((size_t)b * SEQ + i0) * SEQ;
#pragma unroll 2
    for (int t = 0; t < 8; ++t) {
        vfloat4 s[TI];
#pragma unroll
        for (int r = 0; r < TI; ++r) s[r] = (vfloat4){0.f, 0.f, 0.f, 0.f};
#pragma unroll
        for (int q = 0; q < NQ; ++q) {
            vfloat4 rj = *((const vfloat4*)(rt + q * SEQ + t * 256) + lane);
#pragma unroll
            for (int r = 0; r < TI; ++r)
                s[r] += rj * ri[r][q];
        }
#pragma unroll
        for (int r = 0; r < TI; ++r) {
            vfloat4 v = sigmoid4(s[r]) * rinv[r];
            *((vfloat4*)(orow0 + (size_t)r * SEQ + t * 256) + lane) = v;  // plain store
        }
    }
}

// ---------------------------------------------------------------------------
extern "C" void kernel_launch(void* const* d_in, const int* in_sizes, int n_in,
                              void* d_out, int out_size, void* d_ws, size_t ws_size,
                              hipStream_t stream) {
    const float* x        = (const float*)d_in[0];  // (8, 2048, 512) fp32
    const float* rotation = (const float*)d_in[1];  // (512, 8) fp32
    float* out = (float*)d_out;                     // (8, 2048, 2048) fp32

    float* rotT = (float*)d_ws;                     // 8 x 8 x 2048 = 512 KiB

    qa_rot<<<NB * 64, 256, 0, stream>>>(x, rotation, rotT);
    qa_scores<<<NB * 128, K2_THREADS, 0, stream>>>(rotT, out);
}

// Round 3
// 171.504 us; speedup vs baseline: 2.7894x; 2.7894x over previous
//
#include <hip/hip_runtime.h>
#include <math.h>

#define EMBED 512
#define NQ 8
#define SEQ 2048
#define NB 8
#define LOG2E 1.4426950408889634f

typedef float vfloat4 __attribute__((ext_vector_type(4)));

// ---------------------------------------------------------------------------
// k1: rotT[b][q][i] = sum_e x[b][i][e] * R[e][q]   (unchanged — at its 32 MiB
// read roofline, ~6 µs). R transposed through LDS (stride 516, conflict-free
// b128); thread (q = tid&7, rslot = tid>>3) does one K=512 dot with vfloat4.
// ---------------------------------------------------------------------------
#define RPAD 516

__global__ __launch_bounds__(256) void qa_rot(
    const float* __restrict__ x, const float* __restrict__ R,
    float* __restrict__ rotT) {
    __shared__ float rt[NQ * RPAD];
#pragma unroll
    for (int m = 0; m < (EMBED * NQ) / 256; ++m) {
        int f = threadIdx.x + m * 256;
        rt[(f & 7) * RPAD + (f >> 3)] = R[f];
    }
    __syncthreads();

    const int q = threadIdx.x & 7;
    const int rslot = threadIdx.x >> 3;           // 0..31
    const int b = blockIdx.x >> 6;                // 64 blocks per batch
    const int i = ((blockIdx.x & 63) << 5) + rslot;

    const vfloat4* __restrict__ xr =
        (const vfloat4*)(x + ((size_t)b * SEQ + i) * EMBED);
    const vfloat4* __restrict__ rr = (const vfloat4*)(rt + q * RPAD);

    vfloat4 acc = {0.f, 0.f, 0.f, 0.f};           // 4 independent chains
#pragma unroll 8
    for (int m = 0; m < EMBED / 4; ++m) {
        acc += xr[m] * rr[m];                     // packed fma
    }
    rotT[(size_t)b * (NQ * SEQ) + (size_t)q * SEQ + i] =
        (acc.x + acc.y) + (acc.z + acc.w);
}

// ---------------------------------------------------------------------------
// k2 v4: scores[b][i][j] = sigmoid(rot_i . rot_j) / rowsum.
//
// Evidence so far:
//   R0 (pv-retained, 512thr, 16 waves/CU)  : k2 ~66 µs
//   R1 (two-pass,    512thr, 16 waves/CU)  : k2 ~66 µs  (2x VALU+trans: no change)
//   R2 (no LDS, global rj)                 : k2 ~370 µs (FETCH=full request volume:
//        the 128 MiB write stream thrashes L2/L3; LDS staging is MANDATORY,
//        stores must stay nontemporal to bypass the caches)
//
// R1 doubling VALU/trans with no effect exonerates compute. Both R0/R1 sat at
// 50% occupancy (64 KiB panel @ 512 thr -> 2 blocks/CU = 4 waves/SIMD): thin
// latency hiding, phases serialize. This version: SAME 64 KiB panel but
// 1024-thread blocks -> 2 blocks/CU = 32 waves/CU = 100% occupancy.
//   - grid 512 = one residency round
//   - TI=2 two-pass recompute keeps live regs ~55; __launch_bounds__(1024,8)
//     caps at 64 VGPR (required for 8 waves/SIMD)
//   - nontemporal stores (R2 lesson: keep writes out of L2/L3)
// Math bit-identical to R0/R1 (same q-order dots, sigmoid, butterfly).
// ---------------------------------------------------------------------------
#define K2_THREADS 1024
#define TI 2
#define ROWS_PER_BLOCK 32   // 16 waves * TI

__device__ __forceinline__ vfloat4 sigmoid4(vfloat4 s) {
    vfloat4 p;
    p.x = __builtin_amdgcn_rcpf(1.f + __builtin_amdgcn_exp2f(-s.x * LOG2E));
    p.y = __builtin_amdgcn_rcpf(1.f + __builtin_amdgcn_exp2f(-s.y * LOG2E));
    p.z = __builtin_amdgcn_rcpf(1.f + __builtin_amdgcn_exp2f(-s.z * LOG2E));
    p.w = __builtin_amdgcn_rcpf(1.f + __builtin_amdgcn_exp2f(-s.w * LOG2E));
    return p;
}

__global__ __launch_bounds__(K2_THREADS, 8) void qa_scores(
    const float* __restrict__ rotT, float* __restrict__ out) {
    __shared__ float lds[NQ * SEQ];               // 64 KiB, [q][j]
    const int b = blockIdx.x >> 6;                // 64 blocks per batch
    const int i0blk = (blockIdx.x & 63) * ROWS_PER_BLOCK;
    const float* __restrict__ rt = rotT + (size_t)b * (NQ * SEQ);

    // Stage rotT[b] (16384 floats) cooperatively, coalesced 16B.
    {
        const vfloat4* __restrict__ src = (const vfloat4*)rt;
        vfloat4* dst = (vfloat4*)lds;
#pragma unroll
        for (int m = 0; m < (NQ * SEQ / 4) / K2_THREADS; ++m)
            dst[threadIdx.x + m * K2_THREADS] = src[threadIdx.x + m * K2_THREADS];
    }
    __syncthreads();

    const int wave = threadIdx.x >> 6;            // 0..15
    const int lane = threadIdx.x & 63;
    const int i0 = i0blk + wave * TI;

    // rot_i for this wave's 2 rows (broadcast LDS reads).
    float ri[TI][NQ];
#pragma unroll
    for (int r = 0; r < TI; ++r)
#pragma unroll
        for (int q = 0; q < NQ; ++q)
            ri[r][q] = lds[q * SEQ + i0 + r];

    // ---- Pass A: rowsums only. Lane owns j = t*256 + 4*lane .. +3. ----
    float rsum[TI] = {0.f, 0.f};
#pragma unroll
    for (int t = 0; t < 8; ++t) {
        vfloat4 s[TI];
#pragma unroll
        for (int r = 0; r < TI; ++r) s[r] = (vfloat4){0.f, 0.f, 0.f, 0.f};
#pragma unroll
        for (int q = 0; q < NQ; ++q) {            // q-outer: one rj live
            vfloat4 rj = *((const vfloat4*)(lds + q * SEQ + t * 256) + lane);
#pragma unroll
            for (int r = 0; r < TI; ++r)
                s[r] += rj * ri[r][q];            // packed fma
        }
#pragma unroll
        for (int r = 0; r < TI; ++r) {
            vfloat4 p = sigmoid4(s[r]);
            rsum[r] += (p.x + p.y) + (p.z + p.w);
        }
    }

    // Butterfly reduce rowsums over 64 lanes; keep inverse.
    float rinv[TI];
#pragma unroll
    for (int r = 0; r < TI; ++r) {
#pragma unroll
        for (int off = 32; off > 0; off >>= 1)
            rsum[r] += __shfl_xor(rsum[r], off);
        rinv[r] = __builtin_amdgcn_rcpf(rsum[r]);
    }

    // ---- Pass B: recompute (bit-identical), normalize, store per tile. ----
    float* __restrict__ orow0 = out + ((size_t)b * SEQ + i0) * SEQ;
#pragma unroll
    for (int t = 0; t < 8; ++t) {
        vfloat4 s[TI];
#pragma unroll
        for (int r = 0; r < TI; ++r) s[r] = (vfloat4){0.f, 0.f, 0.f, 0.f};
#pragma unroll
        for (int q = 0; q < NQ; ++q) {
            vfloat4 rj = *((const vfloat4*)(lds + q * SEQ + t * 256) + lane);
#pragma unroll
            for (int r = 0; r < TI; ++r)
                s[r] += rj * ri[r][q];
        }
#pragma unroll
        for (int r = 0; r < TI; ++r) {
            vfloat4 v = sigmoid4(s[r]) * rinv[r];
            __builtin_nontemporal_store(
                v, (vfloat4*)(orow0 + (size_t)r * SEQ + t * 256) + lane);
        }
    }
}

// ---------------------------------------------------------------------------
extern "C" void kernel_launch(void* const* d_in, const int* in_sizes, int n_in,
                              void* d_out, int out_size, void* d_ws, size_t ws_size,
                              hipStream_t stream) {
    const float* x        = (const float*)d_in[0];  // (8, 2048, 512) fp32
    const float* rotation = (const float*)d_in[1];  // (512, 8) fp32
    float* out = (float*)d_out;                     // (8, 2048, 2048) fp32

    float* rotT = (float*)d_ws;                     // 8 x 8 x 2048 = 512 KiB

    qa_rot<<<NB * 64, 256, 0, stream>>>(x, rotation, rotT);
    qa_scores<<<NB * 64, K2_THREADS, 0, stream>>>(rotT, out);
}

// Round 4
// 168.105 us; speedup vs baseline: 2.8458x; 1.0202x over previous
//
#include <hip/hip_runtime.h>
#include <math.h>

#define EMBED 512
#define NQ 8
#define SEQ 2048
#define NB 8
#define LOG2E 1.4426950408889634f

typedef float vfloat4 __attribute__((ext_vector_type(4)));

// ---------------------------------------------------------------------------
// k1: rotT[b][q][i] = sum_e x[b][i][e] * R[e][q]   (unchanged — at its 32 MiB
// read roofline, ~6 µs). R transposed through LDS (stride 516, conflict-free
// b128); thread (q = tid&7, rslot = tid>>3) does one K=512 dot with vfloat4.
// ---------------------------------------------------------------------------
#define RPAD 516

__global__ __launch_bounds__(256) void qa_rot(
    const float* __restrict__ x, const float* __restrict__ R,
    float* __restrict__ rotT) {
    __shared__ float rt[NQ * RPAD];
#pragma unroll
    for (int m = 0; m < (EMBED * NQ) / 256; ++m) {
        int f = threadIdx.x + m * 256;
        rt[(f & 7) * RPAD + (f >> 3)] = R[f];
    }
    __syncthreads();

    const int q = threadIdx.x & 7;
    const int rslot = threadIdx.x >> 3;           // 0..31
    const int b = blockIdx.x >> 6;                // 64 blocks per batch
    const int i = ((blockIdx.x & 63) << 5) + rslot;

    const vfloat4* __restrict__ xr =
        (const vfloat4*)(x + ((size_t)b * SEQ + i) * EMBED);
    const vfloat4* __restrict__ rr = (const vfloat4*)(rt + q * RPAD);

    vfloat4 acc = {0.f, 0.f, 0.f, 0.f};           // 4 independent chains
#pragma unroll 8
    for (int m = 0; m < EMBED / 4; ++m) {
        acc += xr[m] * rr[m];                     // packed fma
    }
    rotT[(size_t)b * (NQ * SEQ) + (size_t)q * SEQ + i] =
        (acc.x + acc.y) + (acc.z + acc.w);
}

// ---------------------------------------------------------------------------
// k2 v5: scores[b][i][j] = sigmoid(rot_i . rot_j) / rowsum.
//
// Evidence ledger (k2 structure -> dur_us total):
//   R0 512thr pv-retained nt-burst, 16 w/CU      : 171.3
//   R1 512thr two-pass nt-spread,  16 w/CU       : 172.6  (2x VALU+trans+LDS: neutral)
//   R2 no-LDS global rj, plain stores            : 478    (write stream thrashes
//                                                          caches; LDS mandatory)
//   R3 1024thr two-pass nt,        32 w/CU       : 171.5  (occupancy: neutral)
//
// Every compute/LDS/occupancy resource has been 2x-perturbed with zero effect.
// The ONLY never-isolated shared feature of the fast variants is the
// NONTEMPORAL store path. The harness fill proves plain 16B/lane stores
// sustain 6.45 TB/s. This version = R3 exactly, with plain (cached) stores —
// single-variable A/B on the store path. The R2 confound (plain stores
// thrashing rot_j reads) does not apply: global rotT reads here are the
// one-shot 32 MiB staging, worst case +5 us if evicted.
// ---------------------------------------------------------------------------
#define K2_THREADS 1024
#define TI 2
#define ROWS_PER_BLOCK 32   // 16 waves * TI

__device__ __forceinline__ vfloat4 sigmoid4(vfloat4 s) {
    vfloat4 p;
    p.x = __builtin_amdgcn_rcpf(1.f + __builtin_amdgcn_exp2f(-s.x * LOG2E));
    p.y = __builtin_amdgcn_rcpf(1.f + __builtin_amdgcn_exp2f(-s.y * LOG2E));
    p.z = __builtin_amdgcn_rcpf(1.f + __builtin_amdgcn_exp2f(-s.z * LOG2E));
    p.w = __builtin_amdgcn_rcpf(1.f + __builtin_amdgcn_exp2f(-s.w * LOG2E));
    return p;
}

__global__ __launch_bounds__(K2_THREADS, 8) void qa_scores(
    const float* __restrict__ rotT, float* __restrict__ out) {
    __shared__ float lds[NQ * SEQ];               // 64 KiB, [q][j]
    const int b = blockIdx.x >> 6;                // 64 blocks per batch
    const int i0blk = (blockIdx.x & 63) * ROWS_PER_BLOCK;
    const float* __restrict__ rt = rotT + (size_t)b * (NQ * SEQ);

    // Stage rotT[b] (16384 floats) cooperatively, coalesced 16B.
    {
        const vfloat4* __restrict__ src = (const vfloat4*)rt;
        vfloat4* dst = (vfloat4*)lds;
#pragma unroll
        for (int m = 0; m < (NQ * SEQ / 4) / K2_THREADS; ++m)
            dst[threadIdx.x + m * K2_THREADS] = src[threadIdx.x + m * K2_THREADS];
    }
    __syncthreads();

    const int wave = threadIdx.x >> 6;            // 0..15
    const int lane = threadIdx.x & 63;
    const int i0 = i0blk + wave * TI;

    // rot_i for this wave's 2 rows (broadcast LDS reads).
    float ri[TI][NQ];
#pragma unroll
    for (int r = 0; r < TI; ++r)
#pragma unroll
        for (int q = 0; q < NQ; ++q)
            ri[r][q] = lds[q * SEQ + i0 + r];

    // ---- Pass A: rowsums only. Lane owns j = t*256 + 4*lane .. +3. ----
    float rsum[TI] = {0.f, 0.f};
#pragma unroll
    for (int t = 0; t < 8; ++t) {
        vfloat4 s[TI];
#pragma unroll
        for (int r = 0; r < TI; ++r) s[r] = (vfloat4){0.f, 0.f, 0.f, 0.f};
#pragma unroll
        for (int q = 0; q < NQ; ++q) {            // q-outer: one rj live
            vfloat4 rj = *((const vfloat4*)(lds + q * SEQ + t * 256) + lane);
#pragma unroll
            for (int r = 0; r < TI; ++r)
                s[r] += rj * ri[r][q];            // packed fma
        }
#pragma unroll
        for (int r = 0; r < TI; ++r) {
            vfloat4 p = sigmoid4(s[r]);
            rsum[r] += (p.x + p.y) + (p.z + p.w);
        }
    }

    // Butterfly reduce rowsums over 64 lanes; keep inverse.
    float rinv[TI];
#pragma unroll
    for (int r = 0; r < TI; ++r) {
#pragma unroll
        for (int off = 32; off > 0; off >>= 1)
            rsum[r] += __shfl_xor(rsum[r], off);
        rinv[r] = __builtin_amdgcn_rcpf(rsum[r]);
    }

    // ---- Pass B: recompute (bit-identical), normalize, store per tile. ----
    float* __restrict__ orow0 = out + ((size_t)b * SEQ + i0) * SEQ;
#pragma unroll
    for (int t = 0; t < 8; ++t) {
        vfloat4 s[TI];
#pragma unroll
        for (int r = 0; r < TI; ++r) s[r] = (vfloat4){0.f, 0.f, 0.f, 0.f};
#pragma unroll
        for (int q = 0; q < NQ; ++q) {
            vfloat4 rj = *((const vfloat4*)(lds + q * SEQ + t * 256) + lane);
#pragma unroll
            for (int r = 0; r < TI; ++r)
                s[r] += rj * ri[r][q];
        }
#pragma unroll
        for (int r = 0; r < TI; ++r) {
            vfloat4 v = sigmoid4(s[r]) * rinv[r];
            *((vfloat4*)(orow0 + (size_t)r * SEQ + t * 256) + lane) = v;  // PLAIN store (A/B vs nt)
        }
    }
}

// ---------------------------------------------------------------------------
extern "C" void kernel_launch(void* const* d_in, const int* in_sizes, int n_in,
                              void* d_out, int out_size, void* d_ws, size_t ws_size,
                              hipStream_t stream) {
    const float* x        = (const float*)d_in[0];  // (8, 2048, 512) fp32
    const float* rotation = (const float*)d_in[1];  // (512, 8) fp32
    float* out = (float*)d_out;                     // (8, 2048, 2048) fp32

    float* rotT = (float*)d_ws;                     // 8 x 8 x 2048 = 512 KiB

    qa_rot<<<NB * 64, 256, 0, stream>>>(x, rotation, rotT);
    qa_scores<<<NB * 64, K2_THREADS, 0, stream>>>(rotT, out);
}